// Round 9
// baseline (917.319 us; speedup 1.0000x reference)
//
#include <hip/hip_runtime.h>
#include <math.h>

// AttnBlock: GroupNorm -> QKV 1x1 conv -> spatial self-attention -> proj 1x1 conv + residual
// x (4, 512, 64, 64) fp32. B=4, C=512, N=HW=4096, 32 groups of 16 ch.
// Round 9: attn loop restructured — V in registers (2-batch prefetch), K in LDS,
// 2 barriers/iter, 4-way split QK accumulator. qkv/proj MFMA kernels unchanged (r8).

#define BATCH 4
#define CH    512
#define NPOS  4096
#define NGRP  32
#define GSIZE (16 * NPOS)
#define WSZ   262144   // 512*512

typedef __attribute__((ext_vector_type(8))) short bf16x8;
typedef __attribute__((ext_vector_type(4))) float f32x4;

__device__ __forceinline__ ushort f2b(float x) {   // fp32 -> bf16 RNE
    uint u = __float_as_uint(x);
    u += 0x7fff + ((u >> 16) & 1);
    return (ushort)(u >> 16);
}

// async global->LDS, 16B per lane (lds base wave-uniform, HW adds lane*16)
__device__ __forceinline__ void gld16(void* lds, const void* g) {
    __builtin_amdgcn_global_load_lds(
        (const __attribute__((address_space(1))) void*)g,
        (__attribute__((address_space(3))) void*)lds, 16, 0, 0);
}

// ---------------------------------------------------------------------------
// K1: GroupNorm statistics. One block per (b, g) contiguous 65536-float segment.
// ---------------------------------------------------------------------------
__global__ __launch_bounds__(256) void gn_stats_k(const float* __restrict__ x,
                                                  float* __restrict__ stats) {
    int bg = blockIdx.x;
    const float4* xp = reinterpret_cast<const float4*>(x + (size_t)bg * GSIZE);
    float s1 = 0.f, s2 = 0.f;
    for (int i = threadIdx.x; i < GSIZE / 4; i += 256) {
        float4 v = xp[i];
        s1 += v.x + v.y + v.z + v.w;
        s2 += v.x * v.x + v.y * v.y + v.z * v.z + v.w * v.w;
    }
    for (int off = 32; off > 0; off >>= 1) {
        s1 += __shfl_down(s1, off);
        s2 += __shfl_down(s2, off);
    }
    __shared__ float r1[4], r2[4];
    int wid = threadIdx.x >> 6;
    if ((threadIdx.x & 63) == 0) { r1[wid] = s1; r2[wid] = s2; }
    __syncthreads();
    if (threadIdx.x == 0) {
        float t1 = r1[0] + r1[1] + r1[2] + r1[3];
        float t2 = r2[0] + r2[1] + r2[2] + r2[3];
        float mean = t1 / (float)GSIZE;
        float var  = t2 / (float)GSIZE - mean * mean;
        stats[bg]       = mean;
        stats[128 + bg] = rsqrtf(var + 1e-6f);
    }
}

// ---------------------------------------------------------------------------
// K2a: weights fp32 -> bf16, W4[sel][o][c], sel = q,k,v,p.
// ---------------------------------------------------------------------------
__global__ __launch_bounds__(256) void wcvt_k(
    const float* __restrict__ Wq, const float* __restrict__ Wk,
    const float* __restrict__ Wv, const float* __restrict__ Wp,
    ushort* __restrict__ W4) {
    int id = blockIdx.x;             // 512 blocks
    int sel = id >> 7, blk = id & 127;
    const float* src = sel == 0 ? Wq : (sel == 1 ? Wk : (sel == 2 ? Wv : Wp));
    const float4* s4 = (const float4*)(src + (size_t)blk * 2048);
    ushort4* d4 = (ushort4*)(W4 + (size_t)sel * WSZ + (size_t)blk * 2048);
    for (int i = threadIdx.x; i < 512; i += 256) {
        float4 v = s4[i];
        d4[i] = make_ushort4(f2b(v.x), f2b(v.y), f2b(v.z), f2b(v.w));
    }
}

// ---------------------------------------------------------------------------
// K2b: GroupNorm apply + transpose: x[b][c][m] fp32 -> hnT[b][m][c] bf16.
// grid (64 mt, 8 ct, 4 b), 64x64 tiles via LDS.
// ---------------------------------------------------------------------------
__global__ __launch_bounds__(256) void hnT_k(
    const float* __restrict__ x, const float* __restrict__ gamma,
    const float* __restrict__ beta, const float* __restrict__ stats,
    ushort* __restrict__ hnT) {
    int bm = blockIdx.x * 64, c0 = blockIdx.y * 64, b = blockIdx.z;
    __shared__ ushort Ls[64][65];
    int t = threadIdx.x, tx = t & 15, ty = t >> 4;
    const float* xb = x + ((size_t)b * CH + c0) * NPOS + bm;
#pragma unroll
    for (int it = 0; it < 4; ++it) {
        int cc = ty + it * 16;
        int ch = c0 + cc;
        int bg = b * NGRP + (ch >> 4);
        float ga = stats[128 + bg] * gamma[ch];
        float be = beta[ch] - stats[bg] * ga;
        float4 v = *(const float4*)(xb + (size_t)cc * NPOS + tx * 4);
        Ls[cc][tx * 4 + 0] = f2b(v.x * ga + be);
        Ls[cc][tx * 4 + 1] = f2b(v.y * ga + be);
        Ls[cc][tx * 4 + 2] = f2b(v.z * ga + be);
        Ls[cc][tx * 4 + 3] = f2b(v.w * ga + be);
    }
    __syncthreads();
#pragma unroll
    for (int it = 0; it < 4; ++it) {
        int mm = ty + it * 16;
        ushort4 o;
        o.x = Ls[tx * 4 + 0][mm];
        o.y = Ls[tx * 4 + 1][mm];
        o.z = Ls[tx * 4 + 2][mm];
        o.w = Ls[tx * 4 + 3][mm];
        *(ushort4*)(hnT + ((size_t)(b * NPOS) + bm + mm) * CH + c0 + tx * 4) = o;
    }
}

// ---------------------------------------------------------------------------
// K3: QKV GEMM on MFMA, no LDS. grid (64 mt, 8 ot, 4 b), 4 waves; wave tile
// 32m x 32o, all 3 outputs. Same regs serve A (rows) for q/k, B (cols) for v.
// Outputs: qT[b][m][o] (pre-scaled), kT[b][m][o], vB[b][o][m].
// ---------------------------------------------------------------------------
__global__ __launch_bounds__(256) void qkv3_k(
    const ushort* __restrict__ hnT, const ushort* __restrict__ W4,
    const float* __restrict__ bq, const float* __restrict__ bk,
    const float* __restrict__ bv,
    ushort* __restrict__ qT, ushort* __restrict__ kT, ushort* __restrict__ vB) {
    int bm = blockIdx.x * 64, bo = blockIdx.y * 64, b = blockIdx.z;
    int t = threadIdx.x, l = t & 63, w = t >> 6;
    int wr = w & 1, wc = w >> 1;
    int lr = l & 15, lg = l >> 4;

    const ushort* ha  = hnT + ((size_t)(b * NPOS) + bm + wr * 32 + lr) * CH + lg * 8;
    const ushort* wqp = W4 + (size_t)(bo + wc * 32 + lr) * CH + lg * 8;
    const ushort* wkp = wqp + WSZ;
    const ushort* wvp = wkp + WSZ;

    f32x4 aq[2][2], ak[2][2], av[2][2];
#pragma unroll
    for (int i = 0; i < 2; ++i)
#pragma unroll
        for (int j = 0; j < 2; ++j) {
            aq[i][j] = (f32x4){0.f, 0.f, 0.f, 0.f};
            ak[i][j] = (f32x4){0.f, 0.f, 0.f, 0.f};
            av[i][j] = (f32x4){0.f, 0.f, 0.f, 0.f};
        }
#pragma unroll
    for (int c0 = 0; c0 < CH; c0 += 32) {
        bf16x8 a0 = *(const bf16x8*)(ha + c0);
        bf16x8 a1 = *(const bf16x8*)(ha + 16 * CH + c0);
        bf16x8 q0 = *(const bf16x8*)(wqp + c0);
        bf16x8 q1 = *(const bf16x8*)(wqp + 16 * CH + c0);
        bf16x8 k0 = *(const bf16x8*)(wkp + c0);
        bf16x8 k1 = *(const bf16x8*)(wkp + 16 * CH + c0);
        bf16x8 v0 = *(const bf16x8*)(wvp + c0);
        bf16x8 v1 = *(const bf16x8*)(wvp + 16 * CH + c0);
        aq[0][0] = __builtin_amdgcn_mfma_f32_16x16x32_bf16(a0, q0, aq[0][0], 0, 0, 0);
        aq[0][1] = __builtin_amdgcn_mfma_f32_16x16x32_bf16(a0, q1, aq[0][1], 0, 0, 0);
        aq[1][0] = __builtin_amdgcn_mfma_f32_16x16x32_bf16(a1, q0, aq[1][0], 0, 0, 0);
        aq[1][1] = __builtin_amdgcn_mfma_f32_16x16x32_bf16(a1, q1, aq[1][1], 0, 0, 0);
        ak[0][0] = __builtin_amdgcn_mfma_f32_16x16x32_bf16(a0, k0, ak[0][0], 0, 0, 0);
        ak[0][1] = __builtin_amdgcn_mfma_f32_16x16x32_bf16(a0, k1, ak[0][1], 0, 0, 0);
        ak[1][0] = __builtin_amdgcn_mfma_f32_16x16x32_bf16(a1, k0, ak[1][0], 0, 0, 0);
        ak[1][1] = __builtin_amdgcn_mfma_f32_16x16x32_bf16(a1, k1, ak[1][1], 0, 0, 0);
        av[0][0] = __builtin_amdgcn_mfma_f32_16x16x32_bf16(v0, a0, av[0][0], 0, 0, 0);
        av[0][1] = __builtin_amdgcn_mfma_f32_16x16x32_bf16(v0, a1, av[0][1], 0, 0, 0);
        av[1][0] = __builtin_amdgcn_mfma_f32_16x16x32_bf16(v1, a0, av[1][0], 0, 0, 0);
        av[1][1] = __builtin_amdgcn_mfma_f32_16x16x32_bf16(v1, a1, av[1][1], 0, 0, 0);
    }
    const float sc = 0.044194173824159216f;   // 512^-0.5 folded into q
#pragma unroll
    for (int j = 0; j < 2; ++j) {
        int o = bo + wc * 32 + j * 16 + lr;
        float bqv = bq[o], bkv = bk[o];
#pragma unroll
        for (int i = 0; i < 2; ++i)
#pragma unroll
            for (int r = 0; r < 4; ++r) {
                int m = bm + wr * 32 + i * 16 + 4 * lg + r;
                size_t base = ((size_t)(b * NPOS) + m) * CH + o;
                qT[base] = f2b((aq[i][j][r] + bqv) * sc);
                kT[base] = f2b(ak[i][j][r] + bkv);
            }
    }
#pragma unroll
    for (int i = 0; i < 2; ++i)
#pragma unroll
        for (int r = 0; r < 4; ++r) {
            int o = bo + wc * 32 + i * 16 + 4 * lg + r;
            float bvv = bv[o];
#pragma unroll
            for (int j = 0; j < 2; ++j) {
                int m = bm + wr * 32 + j * 16 + lr;
                vB[((size_t)(b * CH) + o) * NPOS + m] = f2b(av[i][j][r] + bvv);
            }
        }
}

// ---------------------------------------------------------------------------
// K4: flash attention v3. 512 blocks x 4 waves. K staged in LDS (XOR swizzle,
// global_load_lds); V fragments prefetched to REGISTERS in two batches
// (A at iter start -> covered by QK; B after b1 -> covered by softmax).
// 2 barriers/iter: b1 (mpart ready / Ks reads done), b2 (P+lpart ready;
// implicit vmcnt(0) drain covers stageK and V-batch completion).
// QK uses a 4-way split accumulator to break the MFMA dependency chain.
// ---------------------------------------------------------------------------
__global__ __launch_bounds__(256, 2) void attn_k(
    const ushort* __restrict__ qT, const ushort* __restrict__ kT,
    const ushort* __restrict__ vB, ushort* __restrict__ aoT) {
    __shared__ ushort Ks[32 * 512];      // 32 KB
    __shared__ ushort P_lds[32 * 40];    // 80B rows
    __shared__ float mpart[2][2][16], lpart[2][2][16];

    int id = blockIdx.x;
    int b  = (id & 7) >> 1;
    int mt = ((id >> 3) << 1) | (id & 1);
    int m0 = mt * 32;

    int t = threadIdx.x, l = t & 63, w = t >> 6;
    int mi = w & 1, ci = w >> 1;
    int lr = l & 15, lg = l >> 4;

    const ushort* kTb = kT + (size_t)b * NPOS * CH;
    const ushort* vBb = vB + (size_t)b * CH * NPOS;

    auto stageK = [&](int n0) {
#pragma unroll
        for (int i = 0; i < 8; ++i) {
            int n = w * 8 + i;
            const ushort* g = kTb + (size_t)(n0 + n) * CH + (l ^ i) * 8;
            gld16(&Ks[n * 512], g);
        }
    };

    stageK(0);

    // V fragment base: lane (lr,lg) reads V[ci*256 + cs*16 + lr][n0 + lg*8 ..+8]
    const ushort* vfrag = vBb + (size_t)(ci * 256 + lr) * NPOS + lg * 8;

    // Q fragments in registers: wave's 16 rows (mi half), full C=512.
    const ushort* qrow = qT + ((size_t)(b * NPOS + m0 + mi * 16 + lr)) * CH + lg * 8;
    bf16x8 qf[16];
#pragma unroll
    for (int ks = 0; ks < 16; ++ks) qf[ks] = *(const bf16x8*)(qrow + ks * 32);

    f32x4 acc[16];
#pragma unroll
    for (int i = 0; i < 16; ++i) acc[i] = (f32x4){0.f, 0.f, 0.f, 0.f};
    float m_run[4], l_run[4];
#pragma unroll
    for (int r = 0; r < 4; ++r) { m_run[r] = -1e30f; l_run[r] = 0.f; }
    __syncthreads();   // staged K tile 0 landed (vmcnt drains before barrier)

    int zk = lr & 7;
    for (int nt = 0; nt < 128; ++nt) {
        int n0 = nt * 32;
        // ---- V batch A prefetch (cs 0..7): covered by QK phase ----
        bf16x8 vfA[8], vfB[8];
#pragma unroll
        for (int cs = 0; cs < 8; ++cs)
            vfA[cs] = *(const bf16x8*)(vfrag + (size_t)(cs * 16) * NPOS + n0);
        // ---- scores: S[16 rows (mi)][16 keys (ci)], 4-way split acc ----
        f32x4 sp0 = {0.f, 0.f, 0.f, 0.f}, sp1 = sp0, sp2 = sp0, sp3 = sp0;
        const ushort* krow = &Ks[(ci * 16 + lr) * 512];
#pragma unroll
        for (int ks = 0; ks < 16; ks += 4) {
            bf16x8 kf0 = *(const bf16x8*)(krow + (((ks + 0) * 4 + lg) ^ zk) * 8);
            bf16x8 kf1 = *(const bf16x8*)(krow + (((ks + 1) * 4 + lg) ^ zk) * 8);
            bf16x8 kf2 = *(const bf16x8*)(krow + (((ks + 2) * 4 + lg) ^ zk) * 8);
            bf16x8 kf3 = *(const bf16x8*)(krow + (((ks + 3) * 4 + lg) ^ zk) * 8);
            sp0 = __builtin_amdgcn_mfma_f32_16x16x32_bf16(qf[ks + 0], kf0, sp0, 0, 0, 0);
            sp1 = __builtin_amdgcn_mfma_f32_16x16x32_bf16(qf[ks + 1], kf1, sp1, 0, 0, 0);
            sp2 = __builtin_amdgcn_mfma_f32_16x16x32_bf16(qf[ks + 2], kf2, sp2, 0, 0, 0);
            sp3 = __builtin_amdgcn_mfma_f32_16x16x32_bf16(qf[ks + 3], kf3, sp3, 0, 0, 0);
        }
        f32x4 s = (sp0 + sp1) + (sp2 + sp3);
        // row-max over this wave's 16 keys (reduce over lr)
        float pm[4];
#pragma unroll
        for (int r = 0; r < 4; ++r) pm[r] = s[r];
#pragma unroll
        for (int off = 1; off < 16; off <<= 1)
#pragma unroll
            for (int r = 0; r < 4; ++r) pm[r] = fmaxf(pm[r], __shfl_xor(pm[r], off));
        if (lr == 0) {
#pragma unroll
            for (int r = 0; r < 4; ++r) mpart[ci][mi][4 * lg + r] = pm[r];
        }
        __syncthreads();                       // b1: mpart ready, Ks reads done
        if (nt + 1 < 128) stageK((nt + 1) * 32);
        // ---- V batch B prefetch (cs 8..15): covered by softmax ----
#pragma unroll
        for (int cs = 0; cs < 8; ++cs)
            vfB[cs] = *(const bf16x8*)(vfrag + (size_t)((cs + 8) * 16) * NPOS + n0);

        float mnew[4], alpha[4], p[4], ps[4];
#pragma unroll
        for (int r = 0; r < 4; ++r) {
            int row = 4 * lg + r;
            float mt2 = fmaxf(mpart[0][mi][row], mpart[1][mi][row]);
            mnew[r]  = fmaxf(m_run[r], mt2);
            alpha[r] = __expf(m_run[r] - mnew[r]);
            m_run[r] = mnew[r];
            p[r]  = __expf(s[r] - mnew[r]);
            ps[r] = p[r];
        }
#pragma unroll
        for (int off = 1; off < 16; off <<= 1)
#pragma unroll
            for (int r = 0; r < 4; ++r) ps[r] += __shfl_xor(ps[r], off);
        if (lr == 0) {
#pragma unroll
            for (int r = 0; r < 4; ++r) lpart[ci][mi][4 * lg + r] = ps[r];
        }
#pragma unroll
        for (int r = 0; r < 4; ++r)
            P_lds[(mi * 16 + 4 * lg + r) * 40 + ci * 16 + lr] = f2b(p[r]);
        // rescale accumulator (VALU, overlaps other waves' P writes)
#pragma unroll
        for (int cs = 0; cs < 16; ++cs) {
            acc[cs][0] *= alpha[0]; acc[cs][1] *= alpha[1];
            acc[cs][2] *= alpha[2]; acc[cs][3] *= alpha[3];
        }
        __syncthreads();                       // b2: P+lpart ready; K(t+1), V landed
#pragma unroll
        for (int r = 0; r < 4; ++r) {
            int row = 4 * lg + r;
            l_run[r] = l_run[r] * alpha[r] + (lpart[0][mi][row] + lpart[1][mi][row]);
        }
        // ---- PV: O[16 rows][256 c-half] += P[16][32] . V(regs) ----
        bf16x8 pa = *(const bf16x8*)&P_lds[(mi * 16 + lr) * 40 + lg * 8];
#pragma unroll
        for (int cs = 0; cs < 8; ++cs)
            acc[cs] = __builtin_amdgcn_mfma_f32_16x16x32_bf16(pa, vfA[cs], acc[cs], 0, 0, 0);
#pragma unroll
        for (int cs = 0; cs < 8; ++cs)
            acc[cs + 8] = __builtin_amdgcn_mfma_f32_16x16x32_bf16(pa, vfB[cs], acc[cs + 8], 0, 0, 0);
    }
    // epilogue: normalize, store bf16 aoT[b][m][c]
    float inv[4];
#pragma unroll
    for (int r = 0; r < 4; ++r) inv[r] = 1.0f / l_run[r];
#pragma unroll
    for (int cs = 0; cs < 16; ++cs)
#pragma unroll
        for (int r = 0; r < 4; ++r)
            aoT[((size_t)(b * NPOS + m0 + mi * 16 + 4 * lg + r)) * CH
                + ci * 256 + cs * 16 + lr] = f2b(acc[cs][r] * inv[r]);
}

// ---------------------------------------------------------------------------
// K5: proj on MFMA + bias + residual. A=Wp (rows o), B=aoT bf16 (cols m).
// grid (64 mt, 8 ot, 4 b), 4 waves, wave tile 32o x 32m. No LDS.
// ---------------------------------------------------------------------------
__global__ __launch_bounds__(256) void proj_k(
    const ushort* __restrict__ aoT, const ushort* __restrict__ W4,
    const float* __restrict__ bp, const float* __restrict__ x,
    float* __restrict__ out) {
    int bm = blockIdx.x * 64, bo = blockIdx.y * 64, b = blockIdx.z;
    int t = threadIdx.x, l = t & 63, w = t >> 6;
    int orh = w & 1, mc = w >> 1;
    int lr = l & 15, lg = l >> 4;

    const ushort* wp = W4 + 3 * (size_t)WSZ + (size_t)(bo + orh * 32 + lr) * CH + lg * 8;
    const ushort* ab = aoT + ((size_t)(b * NPOS) + bm + mc * 32 + lr) * CH + lg * 8;

    f32x4 ac[2][2];
#pragma unroll
    for (int i = 0; i < 2; ++i)
#pragma unroll
        for (int j = 0; j < 2; ++j) ac[i][j] = (f32x4){0.f, 0.f, 0.f, 0.f};
#pragma unroll
    for (int c0 = 0; c0 < CH; c0 += 32) {
        bf16x8 w0 = *(const bf16x8*)(wp + c0);
        bf16x8 w1 = *(const bf16x8*)(wp + 16 * CH + c0);
        bf16x8 b0 = *(const bf16x8*)(ab + c0);
        bf16x8 b1 = *(const bf16x8*)(ab + 16 * CH + c0);
        ac[0][0] = __builtin_amdgcn_mfma_f32_16x16x32_bf16(w0, b0, ac[0][0], 0, 0, 0);
        ac[0][1] = __builtin_amdgcn_mfma_f32_16x16x32_bf16(w0, b1, ac[0][1], 0, 0, 0);
        ac[1][0] = __builtin_amdgcn_mfma_f32_16x16x32_bf16(w1, b0, ac[1][0], 0, 0, 0);
        ac[1][1] = __builtin_amdgcn_mfma_f32_16x16x32_bf16(w1, b1, ac[1][1], 0, 0, 0);
    }
#pragma unroll
    for (int i = 0; i < 2; ++i)
#pragma unroll
        for (int r = 0; r < 4; ++r) {
            int o = bo + orh * 32 + i * 16 + 4 * lg + r;
            float bpv = bp[o];
#pragma unroll
            for (int j = 0; j < 2; ++j) {
                int m = bm + mc * 32 + j * 16 + lr;
                size_t base = ((size_t)(b * CH) + o) * NPOS + m;
                out[base] = ac[i][j][r] + bpv + x[base];
            }
        }
}

// ---------------------------------------------------------------------------
extern "C" void kernel_launch(void* const* d_in, const int* in_sizes, int n_in,
                              void* d_out, int out_size, void* d_ws, size_t ws_size,
                              hipStream_t stream) {
    const float* x     = (const float*)d_in[0];
    const float* gamma = (const float*)d_in[1];
    const float* beta  = (const float*)d_in[2];
    const float* Wq    = (const float*)d_in[3];
    const float* bq    = (const float*)d_in[4];
    const float* Wk    = (const float*)d_in[5];
    const float* bk    = (const float*)d_in[6];
    const float* Wv    = (const float*)d_in[7];
    const float* bv    = (const float*)d_in[8];
    const float* Wp    = (const float*)d_in[9];
    const float* bp    = (const float*)d_in[10];
    float* out = (float*)d_out;

    const size_t SZ = (size_t)BATCH * CH * NPOS;               // 8,388,608
    const size_t need = (5 * SZ + 4 * WSZ) * 2 + 1024;         // ~86 MB
    if (ws_size < need) return;

    ushort* qT  = (ushort*)d_ws;          // [b][m][o] bf16 (pre-scaled)
    ushort* kT  = qT + SZ;                // [b][m][o] bf16
    ushort* vb  = kT + SZ;                // [b][o][m] bf16
    ushort* hnT = vb + SZ;                // [b][m][c] bf16
    ushort* aoT = hnT + SZ;               // [b][m][c] bf16
    ushort* W4  = aoT + SZ;               // [4][512][512] bf16
    float*  stats = (float*)(W4 + 4 * (size_t)WSZ);

    gn_stats_k<<<128, 256, 0, stream>>>(x, stats);
    wcvt_k<<<512, 256, 0, stream>>>(Wq, Wk, Wv, Wp, W4);
    hnT_k<<<dim3(64, 8, 4), 256, 0, stream>>>(x, gamma, beta, stats, hnT);
    qkv3_k<<<dim3(64, 8, 4), 256, 0, stream>>>(hnT, W4, bq, bk, bv, qT, kT, vb);
    attn_k<<<dim3(512), 256, 0, stream>>>(qT, kT, vb, aoT);
    proj_k<<<dim3(64, 8, 4), 256, 0, stream>>>(aoT, W4, bp, x, out);
}

// Round 10
// 557.774 us; speedup vs baseline: 1.6446x; 1.6446x over previous
//
#include <hip/hip_runtime.h>
#include <math.h>

// AttnBlock: GroupNorm -> QKV 1x1 conv -> spatial self-attention -> proj 1x1 conv + residual
// x (4, 512, 64, 64) fp32. B=4, C=512, N=HW=4096, 32 groups of 16 ch.
// Round 10: attn v4 — 8-wave M_BLK=64 blocks (grid 256, 1/CU), V+P double-buffered
// in LDS, 2 barriers/iter (stage issue covered by softmax), 4-way split QK acc.
// r9 lesson: register "prefetch" is compiler fiction; dbuf LDS is the mechanism.

#define BATCH 4
#define CH    512
#define NPOS  4096
#define NGRP  32
#define GSIZE (16 * NPOS)
#define WSZ   262144   // 512*512

typedef __attribute__((ext_vector_type(8))) short bf16x8;
typedef __attribute__((ext_vector_type(4))) float f32x4;

__device__ __forceinline__ ushort f2b(float x) {   // fp32 -> bf16 RNE
    uint u = __float_as_uint(x);
    u += 0x7fff + ((u >> 16) & 1);
    return (ushort)(u >> 16);
}

// async global->LDS, 16B per lane (lds base wave-uniform, HW adds lane*16)
__device__ __forceinline__ void gld16(void* lds, const void* g) {
    __builtin_amdgcn_global_load_lds(
        (const __attribute__((address_space(1))) void*)g,
        (__attribute__((address_space(3))) void*)lds, 16, 0, 0);
}

// ---------------------------------------------------------------------------
// K1: GroupNorm statistics. One block per (b, g) contiguous 65536-float segment.
// ---------------------------------------------------------------------------
__global__ __launch_bounds__(256) void gn_stats_k(const float* __restrict__ x,
                                                  float* __restrict__ stats) {
    int bg = blockIdx.x;
    const float4* xp = reinterpret_cast<const float4*>(x + (size_t)bg * GSIZE);
    float s1 = 0.f, s2 = 0.f;
    for (int i = threadIdx.x; i < GSIZE / 4; i += 256) {
        float4 v = xp[i];
        s1 += v.x + v.y + v.z + v.w;
        s2 += v.x * v.x + v.y * v.y + v.z * v.z + v.w * v.w;
    }
    for (int off = 32; off > 0; off >>= 1) {
        s1 += __shfl_down(s1, off);
        s2 += __shfl_down(s2, off);
    }
    __shared__ float r1[4], r2[4];
    int wid = threadIdx.x >> 6;
    if ((threadIdx.x & 63) == 0) { r1[wid] = s1; r2[wid] = s2; }
    __syncthreads();
    if (threadIdx.x == 0) {
        float t1 = r1[0] + r1[1] + r1[2] + r1[3];
        float t2 = r2[0] + r2[1] + r2[2] + r2[3];
        float mean = t1 / (float)GSIZE;
        float var  = t2 / (float)GSIZE - mean * mean;
        stats[bg]       = mean;
        stats[128 + bg] = rsqrtf(var + 1e-6f);
    }
}

// ---------------------------------------------------------------------------
// K2a: weights fp32 -> bf16, W4[sel][o][c], sel = q,k,v,p.
// ---------------------------------------------------------------------------
__global__ __launch_bounds__(256) void wcvt_k(
    const float* __restrict__ Wq, const float* __restrict__ Wk,
    const float* __restrict__ Wv, const float* __restrict__ Wp,
    ushort* __restrict__ W4) {
    int id = blockIdx.x;             // 512 blocks
    int sel = id >> 7, blk = id & 127;
    const float* src = sel == 0 ? Wq : (sel == 1 ? Wk : (sel == 2 ? Wv : Wp));
    const float4* s4 = (const float4*)(src + (size_t)blk * 2048);
    ushort4* d4 = (ushort4*)(W4 + (size_t)sel * WSZ + (size_t)blk * 2048);
    for (int i = threadIdx.x; i < 512; i += 256) {
        float4 v = s4[i];
        d4[i] = make_ushort4(f2b(v.x), f2b(v.y), f2b(v.z), f2b(v.w));
    }
}

// ---------------------------------------------------------------------------
// K2b: GroupNorm apply + transpose: x[b][c][m] fp32 -> hnT[b][m][c] bf16.
// grid (64 mt, 8 ct, 4 b), 64x64 tiles via LDS.
// ---------------------------------------------------------------------------
__global__ __launch_bounds__(256) void hnT_k(
    const float* __restrict__ x, const float* __restrict__ gamma,
    const float* __restrict__ beta, const float* __restrict__ stats,
    ushort* __restrict__ hnT) {
    int bm = blockIdx.x * 64, c0 = blockIdx.y * 64, b = blockIdx.z;
    __shared__ ushort Ls[64][65];
    int t = threadIdx.x, tx = t & 15, ty = t >> 4;
    const float* xb = x + ((size_t)b * CH + c0) * NPOS + bm;
#pragma unroll
    for (int it = 0; it < 4; ++it) {
        int cc = ty + it * 16;
        int ch = c0 + cc;
        int bg = b * NGRP + (ch >> 4);
        float ga = stats[128 + bg] * gamma[ch];
        float be = beta[ch] - stats[bg] * ga;
        float4 v = *(const float4*)(xb + (size_t)cc * NPOS + tx * 4);
        Ls[cc][tx * 4 + 0] = f2b(v.x * ga + be);
        Ls[cc][tx * 4 + 1] = f2b(v.y * ga + be);
        Ls[cc][tx * 4 + 2] = f2b(v.z * ga + be);
        Ls[cc][tx * 4 + 3] = f2b(v.w * ga + be);
    }
    __syncthreads();
#pragma unroll
    for (int it = 0; it < 4; ++it) {
        int mm = ty + it * 16;
        ushort4 o;
        o.x = Ls[tx * 4 + 0][mm];
        o.y = Ls[tx * 4 + 1][mm];
        o.z = Ls[tx * 4 + 2][mm];
        o.w = Ls[tx * 4 + 3][mm];
        *(ushort4*)(hnT + ((size_t)(b * NPOS) + bm + mm) * CH + c0 + tx * 4) = o;
    }
}

// ---------------------------------------------------------------------------
// K3: QKV GEMM on MFMA, no LDS. grid (64 mt, 8 ot, 4 b), 4 waves; wave tile
// 32m x 32o, all 3 outputs. Same regs serve A (rows) for q/k, B (cols) for v.
// Outputs: qT[b][m][o] (pre-scaled), kT[b][m][o], vB[b][o][m].
// ---------------------------------------------------------------------------
__global__ __launch_bounds__(256) void qkv3_k(
    const ushort* __restrict__ hnT, const ushort* __restrict__ W4,
    const float* __restrict__ bq, const float* __restrict__ bk,
    const float* __restrict__ bv,
    ushort* __restrict__ qT, ushort* __restrict__ kT, ushort* __restrict__ vB) {
    int bm = blockIdx.x * 64, bo = blockIdx.y * 64, b = blockIdx.z;
    int t = threadIdx.x, l = t & 63, w = t >> 6;
    int wr = w & 1, wc = w >> 1;
    int lr = l & 15, lg = l >> 4;

    const ushort* ha  = hnT + ((size_t)(b * NPOS) + bm + wr * 32 + lr) * CH + lg * 8;
    const ushort* wqp = W4 + (size_t)(bo + wc * 32 + lr) * CH + lg * 8;
    const ushort* wkp = wqp + WSZ;
    const ushort* wvp = wkp + WSZ;

    f32x4 aq[2][2], ak[2][2], av[2][2];
#pragma unroll
    for (int i = 0; i < 2; ++i)
#pragma unroll
        for (int j = 0; j < 2; ++j) {
            aq[i][j] = (f32x4){0.f, 0.f, 0.f, 0.f};
            ak[i][j] = (f32x4){0.f, 0.f, 0.f, 0.f};
            av[i][j] = (f32x4){0.f, 0.f, 0.f, 0.f};
        }
#pragma unroll
    for (int c0 = 0; c0 < CH; c0 += 32) {
        bf16x8 a0 = *(const bf16x8*)(ha + c0);
        bf16x8 a1 = *(const bf16x8*)(ha + 16 * CH + c0);
        bf16x8 q0 = *(const bf16x8*)(wqp + c0);
        bf16x8 q1 = *(const bf16x8*)(wqp + 16 * CH + c0);
        bf16x8 k0 = *(const bf16x8*)(wkp + c0);
        bf16x8 k1 = *(const bf16x8*)(wkp + 16 * CH + c0);
        bf16x8 v0 = *(const bf16x8*)(wvp + c0);
        bf16x8 v1 = *(const bf16x8*)(wvp + 16 * CH + c0);
        aq[0][0] = __builtin_amdgcn_mfma_f32_16x16x32_bf16(a0, q0, aq[0][0], 0, 0, 0);
        aq[0][1] = __builtin_amdgcn_mfma_f32_16x16x32_bf16(a0, q1, aq[0][1], 0, 0, 0);
        aq[1][0] = __builtin_amdgcn_mfma_f32_16x16x32_bf16(a1, q0, aq[1][0], 0, 0, 0);
        aq[1][1] = __builtin_amdgcn_mfma_f32_16x16x32_bf16(a1, q1, aq[1][1], 0, 0, 0);
        ak[0][0] = __builtin_amdgcn_mfma_f32_16x16x32_bf16(a0, k0, ak[0][0], 0, 0, 0);
        ak[0][1] = __builtin_amdgcn_mfma_f32_16x16x32_bf16(a0, k1, ak[0][1], 0, 0, 0);
        ak[1][0] = __builtin_amdgcn_mfma_f32_16x16x32_bf16(a1, k0, ak[1][0], 0, 0, 0);
        ak[1][1] = __builtin_amdgcn_mfma_f32_16x16x32_bf16(a1, k1, ak[1][1], 0, 0, 0);
        av[0][0] = __builtin_amdgcn_mfma_f32_16x16x32_bf16(v0, a0, av[0][0], 0, 0, 0);
        av[0][1] = __builtin_amdgcn_mfma_f32_16x16x32_bf16(v0, a1, av[0][1], 0, 0, 0);
        av[1][0] = __builtin_amdgcn_mfma_f32_16x16x32_bf16(v1, a0, av[1][0], 0, 0, 0);
        av[1][1] = __builtin_amdgcn_mfma_f32_16x16x32_bf16(v1, a1, av[1][1], 0, 0, 0);
    }
    const float sc = 0.044194173824159216f;   // 512^-0.5 folded into q
#pragma unroll
    for (int j = 0; j < 2; ++j) {
        int o = bo + wc * 32 + j * 16 + lr;
        float bqv = bq[o], bkv = bk[o];
#pragma unroll
        for (int i = 0; i < 2; ++i)
#pragma unroll
            for (int r = 0; r < 4; ++r) {
                int m = bm + wr * 32 + i * 16 + 4 * lg + r;
                size_t base = ((size_t)(b * NPOS) + m) * CH + o;
                qT[base] = f2b((aq[i][j][r] + bqv) * sc);
                kT[base] = f2b(ak[i][j][r] + bkv);
            }
    }
#pragma unroll
    for (int i = 0; i < 2; ++i)
#pragma unroll
        for (int r = 0; r < 4; ++r) {
            int o = bo + wc * 32 + i * 16 + 4 * lg + r;
            float bvv = bv[o];
#pragma unroll
            for (int j = 0; j < 2; ++j) {
                int m = bm + wr * 32 + j * 16 + lr;
                vB[((size_t)(b * CH) + o) * NPOS + m] = f2b(av[i][j][r] + bvv);
            }
        }
}

// ---------------------------------------------------------------------------
// K4: flash attention v4. 256 blocks x 512 threads (8 waves, 1 block/CU).
// Wave w: mi=w&3 (16-row quarter of M_BLK=64), ci=w>>2 (n-half for scores,
// c-half for PV). K staged [32][512] (XOR-swz) single-buffered; V staged
// [512][32] DOUBLE-buffered; P [64][40] double-buffered. 2 barriers/iter:
//   QK -> b1 -> stageK(t+1)+stageV(t+1->alt) -> softmax/P-write/rescale
//   -> b2 (vmcnt drain = stages landed) -> l_run + PV. Stage latency is
//   covered by softmax; all LDS RAW/WAR pairs separated by b1/b2 (audited).
// ---------------------------------------------------------------------------
__global__ __launch_bounds__(512, 2) void attn_k(
    const ushort* __restrict__ qT, const ushort* __restrict__ kT,
    const ushort* __restrict__ vB, ushort* __restrict__ aoT) {
    __shared__ ushort Ks[32 * 512];        // 32 KB
    __shared__ ushort Vs[2][512 * 32];     // 64 KB (double buffer)
    __shared__ ushort P_lds[2][64 * 40];   // 10 KB (double buffer), 80B rows
    __shared__ float mpart[2][4][16], lpart[2][4][16];

    // XCD batch clustering: id%8 -> XCD; pairs of XCDs share one batch.
    int id = blockIdx.x;
    int b  = (id & 7) >> 1;
    int mt = ((id >> 3) << 1) | (id & 1);   // 0..63
    int m0 = mt * 64;

    int t = threadIdx.x, l = t & 63, w = t >> 6;   // w 0..7
    int mi = w & 3, ci = w >> 2;
    int lr = l & 15, lg = l >> 4;

    const ushort* kTb = kT + (size_t)b * NPOS * CH;
    const ushort* vBb = vB + (size_t)b * CH * NPOS;

    auto stageK = [&](int n0) {
#pragma unroll
        for (int i = 0; i < 4; ++i) {
            int n = w * 4 + i;
            const ushort* g = kTb + (size_t)(n0 + n) * CH + (l ^ (n & 7)) * 8;
            gld16(&Ks[n * 512], g);
        }
    };
    auto stageV = [&](int n0, ushort* vbuf) {
#pragma unroll
        for (int i = 0; i < 4; ++i) {
            int cb = w * 64 + i * 16;
            int c  = cb + (l >> 2);
            int sc = (l & 3) ^ ((c >> 1) & 3);
            const ushort* g = vBb + (size_t)c * NPOS + n0 + sc * 8;
            gld16(&vbuf[cb * 32], g);
        }
    };

    stageK(0);
    stageV(0, &Vs[0][0]);

    // Q fragments: wave's 16 rows (mi quarter), full C=512.
    const ushort* qrow = qT + ((size_t)(b * NPOS + m0 + mi * 16 + lr)) * CH + lg * 8;
    bf16x8 qf[16];
#pragma unroll
    for (int ks = 0; ks < 16; ++ks) qf[ks] = *(const bf16x8*)(qrow + ks * 32);

    f32x4 acc[16];
#pragma unroll
    for (int i = 0; i < 16; ++i) acc[i] = (f32x4){0.f, 0.f, 0.f, 0.f};
    float m_run[4], l_run[4];
#pragma unroll
    for (int r = 0; r < 4; ++r) { m_run[r] = -1e30f; l_run[r] = 0.f; }
    __syncthreads();   // prologue: K(0), V(0) landed (vmcnt drains at barrier)

    int zk = lr & 7;
    for (int nt = 0; nt < 128; ++nt) {
        const ushort* vs_cur = &Vs[nt & 1][0];
        ushort*       p_cur  = &P_lds[nt & 1][0];
        // ---- scores: S[16 rows (mi)][16 keys (ci)], 4-way split acc ----
        f32x4 sp0 = {0.f, 0.f, 0.f, 0.f}, sp1 = sp0, sp2 = sp0, sp3 = sp0;
        const ushort* krow = &Ks[(ci * 16 + lr) * 512];
#pragma unroll
        for (int ks = 0; ks < 16; ks += 4) {
            bf16x8 kf0 = *(const bf16x8*)(krow + (((ks + 0) * 4 + lg) ^ zk) * 8);
            bf16x8 kf1 = *(const bf16x8*)(krow + (((ks + 1) * 4 + lg) ^ zk) * 8);
            bf16x8 kf2 = *(const bf16x8*)(krow + (((ks + 2) * 4 + lg) ^ zk) * 8);
            bf16x8 kf3 = *(const bf16x8*)(krow + (((ks + 3) * 4 + lg) ^ zk) * 8);
            sp0 = __builtin_amdgcn_mfma_f32_16x16x32_bf16(qf[ks + 0], kf0, sp0, 0, 0, 0);
            sp1 = __builtin_amdgcn_mfma_f32_16x16x32_bf16(qf[ks + 1], kf1, sp1, 0, 0, 0);
            sp2 = __builtin_amdgcn_mfma_f32_16x16x32_bf16(qf[ks + 2], kf2, sp2, 0, 0, 0);
            sp3 = __builtin_amdgcn_mfma_f32_16x16x32_bf16(qf[ks + 3], kf3, sp3, 0, 0, 0);
        }
        f32x4 s = (sp0 + sp1) + (sp2 + sp3);
        // row-max over this wave's 16 keys (reduce over lr)
        float pm[4];
#pragma unroll
        for (int r = 0; r < 4; ++r) pm[r] = s[r];
#pragma unroll
        for (int off = 1; off < 16; off <<= 1)
#pragma unroll
            for (int r = 0; r < 4; ++r) pm[r] = fmaxf(pm[r], __shfl_xor(pm[r], off));
        if (lr == 0) {
#pragma unroll
            for (int r = 0; r < 4; ++r) mpart[ci][mi][4 * lg + r] = pm[r];
        }
        __syncthreads();                       // b1: mpart ready; Ks reads done
        if (nt + 1 < 128) {                    // stages covered by softmax below
            stageK((nt + 1) * 32);
            stageV((nt + 1) * 32, &Vs[(nt + 1) & 1][0]);
        }
        float mnew[4], alpha[4], p[4], ps[4];
#pragma unroll
        for (int r = 0; r < 4; ++r) {
            int row = 4 * lg + r;
            float mt2 = fmaxf(mpart[0][mi][row], mpart[1][mi][row]);
            mnew[r]  = fmaxf(m_run[r], mt2);
            alpha[r] = __expf(m_run[r] - mnew[r]);
            m_run[r] = mnew[r];
            p[r]  = __expf(s[r] - mnew[r]);
            ps[r] = p[r];
        }
#pragma unroll
        for (int off = 1; off < 16; off <<= 1)
#pragma unroll
            for (int r = 0; r < 4; ++r) ps[r] += __shfl_xor(ps[r], off);
        if (lr == 0) {
#pragma unroll
            for (int r = 0; r < 4; ++r) lpart[ci][mi][4 * lg + r] = ps[r];
        }
#pragma unroll
        for (int r = 0; r < 4; ++r)
            p_cur[(mi * 16 + 4 * lg + r) * 40 + ci * 16 + lr] = f2b(p[r]);
        // rescale accumulator (VALU; also covers stage latency)
#pragma unroll
        for (int cs = 0; cs < 16; ++cs) {
            acc[cs][0] *= alpha[0]; acc[cs][1] *= alpha[1];
            acc[cs][2] *= alpha[2]; acc[cs][3] *= alpha[3];
        }
        __syncthreads();                       // b2: P+lpart ready; stages landed
#pragma unroll
        for (int r = 0; r < 4; ++r) {
            int row = 4 * lg + r;
            l_run[r] = l_run[r] * alpha[r] + (lpart[0][mi][row] + lpart[1][mi][row]);
        }
        // ---- PV: O[16 rows][256 c-half] += P[16][32] . V ----
        bf16x8 pa = *(const bf16x8*)&p_cur[(mi * 16 + lr) * 40 + lg * 8];
#pragma unroll
        for (int cs = 0; cs < 16; ++cs) {
            int c = ci * 256 + cs * 16 + lr;
            bf16x8 vf = *(const bf16x8*)&vs_cur[c * 32 + ((lg ^ ((c >> 1) & 3)) * 8)];
            acc[cs] = __builtin_amdgcn_mfma_f32_16x16x32_bf16(pa, vf, acc[cs], 0, 0, 0);
        }
    }
    // epilogue: normalize, store bf16 aoT[b][m][c]
    float inv[4];
#pragma unroll
    for (int r = 0; r < 4; ++r) inv[r] = 1.0f / l_run[r];
#pragma unroll
    for (int cs = 0; cs < 16; ++cs)
#pragma unroll
        for (int r = 0; r < 4; ++r)
            aoT[((size_t)(b * NPOS + m0 + mi * 16 + 4 * lg + r)) * CH
                + ci * 256 + cs * 16 + lr] = f2b(acc[cs][r] * inv[r]);
}

// ---------------------------------------------------------------------------
// K5: proj on MFMA + bias + residual. A=Wp (rows o), B=aoT bf16 (cols m).
// grid (64 mt, 8 ot, 4 b), 4 waves, wave tile 32o x 32m. No LDS.
// ---------------------------------------------------------------------------
__global__ __launch_bounds__(256) void proj_k(
    const ushort* __restrict__ aoT, const ushort* __restrict__ W4,
    const float* __restrict__ bp, const float* __restrict__ x,
    float* __restrict__ out) {
    int bm = blockIdx.x * 64, bo = blockIdx.y * 64, b = blockIdx.z;
    int t = threadIdx.x, l = t & 63, w = t >> 6;
    int orh = w & 1, mc = w >> 1;
    int lr = l & 15, lg = l >> 4;

    const ushort* wp = W4 + 3 * (size_t)WSZ + (size_t)(bo + orh * 32 + lr) * CH + lg * 8;
    const ushort* ab = aoT + ((size_t)(b * NPOS) + bm + mc * 32 + lr) * CH + lg * 8;

    f32x4 ac[2][2];
#pragma unroll
    for (int i = 0; i < 2; ++i)
#pragma unroll
        for (int j = 0; j < 2; ++j) ac[i][j] = (f32x4){0.f, 0.f, 0.f, 0.f};
#pragma unroll
    for (int c0 = 0; c0 < CH; c0 += 32) {
        bf16x8 w0 = *(const bf16x8*)(wp + c0);
        bf16x8 w1 = *(const bf16x8*)(wp + 16 * CH + c0);
        bf16x8 b0 = *(const bf16x8*)(ab + c0);
        bf16x8 b1 = *(const bf16x8*)(ab + 16 * CH + c0);
        ac[0][0] = __builtin_amdgcn_mfma_f32_16x16x32_bf16(w0, b0, ac[0][0], 0, 0, 0);
        ac[0][1] = __builtin_amdgcn_mfma_f32_16x16x32_bf16(w0, b1, ac[0][1], 0, 0, 0);
        ac[1][0] = __builtin_amdgcn_mfma_f32_16x16x32_bf16(w1, b0, ac[1][0], 0, 0, 0);
        ac[1][1] = __builtin_amdgcn_mfma_f32_16x16x32_bf16(w1, b1, ac[1][1], 0, 0, 0);
    }
#pragma unroll
    for (int i = 0; i < 2; ++i)
#pragma unroll
        for (int r = 0; r < 4; ++r) {
            int o = bo + orh * 32 + i * 16 + 4 * lg + r;
            float bpv = bp[o];
#pragma unroll
            for (int j = 0; j < 2; ++j) {
                int m = bm + mc * 32 + j * 16 + lr;
                size_t base = ((size_t)(b * CH) + o) * NPOS + m;
                out[base] = ac[i][j][r] + bpv + x[base];
            }
        }
}

// ---------------------------------------------------------------------------
extern "C" void kernel_launch(void* const* d_in, const int* in_sizes, int n_in,
                              void* d_out, int out_size, void* d_ws, size_t ws_size,
                              hipStream_t stream) {
    const float* x     = (const float*)d_in[0];
    const float* gamma = (const float*)d_in[1];
    const float* beta  = (const float*)d_in[2];
    const float* Wq    = (const float*)d_in[3];
    const float* bq    = (const float*)d_in[4];
    const float* Wk    = (const float*)d_in[5];
    const float* bk    = (const float*)d_in[6];
    const float* Wv    = (const float*)d_in[7];
    const float* bv    = (const float*)d_in[8];
    const float* Wp    = (const float*)d_in[9];
    const float* bp    = (const float*)d_in[10];
    float* out = (float*)d_out;

    const size_t SZ = (size_t)BATCH * CH * NPOS;               // 8,388,608
    const size_t need = (5 * SZ + 4 * WSZ) * 2 + 1024;         // ~86 MB
    if (ws_size < need) return;

    ushort* qT  = (ushort*)d_ws;          // [b][m][o] bf16 (pre-scaled)
    ushort* kT  = qT + SZ;                // [b][m][o] bf16
    ushort* vb  = kT + SZ;                // [b][o][m] bf16
    ushort* hnT = vb + SZ;                // [b][m][c] bf16
    ushort* aoT = hnT + SZ;               // [b][m][c] bf16
    ushort* W4  = aoT + SZ;               // [4][512][512] bf16
    float*  stats = (float*)(W4 + 4 * (size_t)WSZ);

    gn_stats_k<<<128, 256, 0, stream>>>(x, stats);
    wcvt_k<<<512, 256, 0, stream>>>(Wq, Wk, Wv, Wp, W4);
    hnT_k<<<dim3(64, 8, 4), 256, 0, stream>>>(x, gamma, beta, stats, hnT);
    qkv3_k<<<dim3(64, 8, 4), 256, 0, stream>>>(hnT, W4, bq, bk, bv, qT, kT, vb);
    attn_k<<<dim3(256), 512, 0, stream>>>(qT, kT, vb, aoT);
    proj_k<<<dim3(64, 8, 4), 256, 0, stream>>>(aoT, W4, bp, x, out);
}